// Round 13
// baseline (31.416 us; speedup 1.0000x reference)
//
#include <hip/hip_runtime.h>
#include <hip/hip_fp16.h>
#include <math.h>

// Problem constants: N=2000 politicians, B=2000 bills, D=32, K(order)=3.
#define NN    2000
#define NB    2000
#define DD    32
#define NOCT  16                   // K=128: octs 0-11 data, 12 poly, 13-15 zero
#define TILE  64                   // block tile: 64 pols x 64 bills
#define GDIM  32                   // 2048/64

typedef _Float16 half8   __attribute__((ext_vector_type(8)));
typedef _Float16 half4   __attribute__((ext_vector_type(4)));
typedef float    float4v __attribute__((ext_vector_type(4)));

__device__ __forceinline__ float dot4(const float4 a, const float4 b) {
    return fmaf(a.x, b.x, fmaf(a.y, b.y, fmaf(a.z, b.z, a.w * b.w)));
}
__device__ __forceinline__ half4 cvt4(const float x, const float y,
                                      const float z, const float w) {
    half4 h; h[0] = (_Float16)x; h[1] = (_Float16)y;
    h[2] = (_Float16)z; h[3] = (_Float16)w; return h;
}

// Single fused kernel: coalesced in-block build (8 threads/row, each wave-load
// = 8 fully-used 128B lines), fp16 MFMA K=128 -> -dist^2/2, logistic epilogue,
// block atomicAdd. Launch pair: 4B memset + this.
__global__ __launch_bounds__(256, 4) void pol2vec_main(
    const int*   __restrict__ events,   // [N,B] 0/1
    const float* __restrict__ tarr,     // [B]
    const float* __restrict__ beta,     // [B]
    const float* __restrict__ gamma,    // [N]
    const float* __restrict__ zb,       // [B,D]
    const float* __restrict__ zp,       // [K,N,D]
    float*       __restrict__ out)      // [1]
{
    __shared__ _Float16 sW[NOCT * TILE * 8];   // 16KB
    __shared__ _Float16 sZ[NOCT * TILE * 8];   // 16KB
    __shared__ float    s_red[4];

    const int tid  = threadIdx.x;
    const int lane = tid & 63;
    const int w    = tid >> 6;
    const int b0   = blockIdx.x * TILE;
    const int n0   = blockIdx.y * TILE;
    const int wr   = (w >> 1) * 32;
    const int wc   = (w & 1) * 32;
    const int l15  = lane & 15;
    const int l4   = lane >> 4;

    // ---- Events gather first: 16 independent loads, latency hides under build.
    unsigned evb = 0u, vb = 0u;
#pragma unroll
    for (int nr = 0; nr < 2; ++nr)
#pragma unroll
    for (int bc = 0; bc < 2; ++bc)
#pragma unroll
    for (int r = 0; r < 4; ++r) {
        const int ng = n0 + wr + 16 * nr + l4 * 4 + r;
        const int bg = b0 + wc + 16 * bc + l15;
        const bool v = (ng < NN) && (bg < NB);
        const size_t idx = v ? ((size_t)ng * NB + bg) : 0;
        const unsigned bit = 1u << (nr * 8 + bc * 4 + r);
        if (v) vb |= bit;
        if (v && events[idx]) evb |= bit;
    }

    // ---- Zero octets 13-15 (both operands).
    if (tid < 3 * TILE) {
        const half8 zz = {};
        *(half8*)(sW + ((size_t)(13 * TILE + tid)) * 8) = zz;
        *(half8*)(sZ + ((size_t)(13 * TILE + tid)) * 8) = zz;
    }

    const int row = tid >> 3;          // 0..31 (row within half-tile)
    const int q   = tid & 7;           // float4 index within 32-dim row
    const int hs  = (q & 1) * 4;       // half4 slot within octet row

    // ---- W side: 2 passes x 3 coalesced float4 loads; same registers feed
    // fragment writes AND the 6 coefficient dots (no redundant reads).
#pragma unroll
    for (int p = 0; p < 2; ++p) {
        const int nl = 32 * p + row;
        const int n  = n0 + nl;
        float4 a4 = {0.f,0.f,0.f,0.f}, b4 = {0.f,0.f,0.f,0.f}, c4 = {0.f,0.f,0.f,0.f};
        if (n < NN) {
            a4 = ((const float4*)(zp + (size_t)n * DD))[q];
            b4 = ((const float4*)(zp + ((size_t)NN + n) * DD))[q];
            c4 = ((const float4*)(zp + ((size_t)2 * NN + n) * DD))[q];
        }
        *(half4*)(sW + ((size_t)((0 + (q >> 1)) * TILE + nl)) * 8 + hs) =
            cvt4(a4.x, a4.y, a4.z, a4.w);
        *(half4*)(sW + ((size_t)((4 + (q >> 1)) * TILE + nl)) * 8 + hs) =
            cvt4(b4.x, b4.y, b4.z, b4.w);
        *(half4*)(sW + ((size_t)((8 + (q >> 1)) * TILE + nl)) * 8 + hs) =
            cvt4(c4.x, c4.y, c4.z, c4.w);

        float paa = dot4(a4, a4), pab = dot4(a4, b4), pac = dot4(a4, c4);
        float pbb = dot4(b4, b4), pbc = dot4(b4, c4), pcc = dot4(c4, c4);
#pragma unroll
        for (int off = 1; off < 8; off <<= 1) {
            paa += __shfl_xor(paa, off); pab += __shfl_xor(pab, off);
            pac += __shfl_xor(pac, off); pbb += __shfl_xor(pbb, off);
            pbc += __shfl_xor(pbc, off); pcc += __shfl_xor(pcc, off);
        }
        if (q == 0) {
            half8 hv = {};
            hv[0] = (_Float16)paa;            // |A|^2
            hv[1] = (_Float16)(2.f * pab);    // 2 A.B
            hv[2] = (_Float16)(pbb + pac);    // |B|^2 + A.C
            hv[3] = (_Float16)pbc;            // B.C
            hv[4] = (_Float16)(0.25f * pcc);  // |C|^2/4
            hv[5] = (_Float16)1.f;
            *(half8*)(sW + ((size_t)(12 * TILE + nl)) * 8) = hv;
        }
    }

    // ---- Zf side: z, t*z, (t^2/2)*z octets + poly row (z2 via shuffles).
#pragma unroll
    for (int p = 0; p < 2; ++p) {
        const int bl = 32 * p + row;
        const int b  = b0 + bl;
        float4 z4 = {0.f,0.f,0.f,0.f};
        float t = 0.f;
        if (b < NB) {
            z4 = ((const float4*)(zb + (size_t)b * DD))[q];
            t  = tarr[b];
        }
        const float th = 0.5f * t * t;
        *(half4*)(sZ + ((size_t)((0 + (q >> 1)) * TILE + bl)) * 8 + hs) =
            cvt4(z4.x, z4.y, z4.z, z4.w);
        *(half4*)(sZ + ((size_t)((4 + (q >> 1)) * TILE + bl)) * 8 + hs) =
            cvt4(t * z4.x, t * z4.y, t * z4.z, t * z4.w);
        *(half4*)(sZ + ((size_t)((8 + (q >> 1)) * TILE + bl)) * 8 + hs) =
            cvt4(th * z4.x, th * z4.y, th * z4.z, th * z4.w);

        float pz2 = dot4(z4, z4);
#pragma unroll
        for (int off = 1; off < 8; off <<= 1) pz2 += __shfl_xor(pz2, off);
        if (q == 0) {
            const float t2 = t * t;
            half8 hv = {};
            hv[0] = (_Float16)(-0.5f);
            hv[1] = (_Float16)(-0.5f * t);
            hv[2] = (_Float16)(-0.5f * t2);
            hv[3] = (_Float16)(-0.5f * t2 * t);
            hv[4] = (_Float16)(-0.5f * t2 * t2);
            hv[5] = (_Float16)(-0.5f * pz2);
            *(half8*)(sZ + ((size_t)(12 * TILE + bl)) * 8) = hv;
        }
    }
    __syncthreads();

    // ---- Fragment loads from LDS (K=128: 4 K-steps). Proven r12 layout.
    half8 af[2][4], bf[2][4];
#pragma unroll
    for (int ks = 0; ks < 4; ++ks) {
        const int oct = 4 * ks + l4;
#pragma unroll
        for (int h = 0; h < 2; ++h) {
            af[h][ks] = *(const half8*)(sW + ((size_t)oct * TILE + wr + 16 * h + l15) * 8);
            bf[h][ks] = *(const half8*)(sZ + ((size_t)oct * TILE + wc + 16 * h + l15) * 8);
        }
    }

    float4v acc[2][2] = {};
#pragma unroll
    for (int nr = 0; nr < 2; ++nr)
#pragma unroll
    for (int bc = 0; bc < 2; ++bc)
#pragma unroll
    for (int ks = 0; ks < 4; ++ks)
        acc[nr][bc] = __builtin_amdgcn_mfma_f32_16x16x32_f16(
            af[nr][ks], bf[bc][ks], acc[nr][bc], 0, 0, 0);

    // ---- Epilogue: acc = -dist^2/2;  L = gamma + beta - dist.
    float accs = 0.f;
#pragma unroll
    for (int bc = 0; bc < 2; ++bc) {
        const int bg = b0 + wc + 16 * bc + l15;
        const float be = beta[bg < NB ? bg : 0];
#pragma unroll
        for (int nr = 0; nr < 2; ++nr) {
#pragma unroll
            for (int r = 0; r < 4; ++r) {
                const int ng = n0 + wr + 16 * nr + l4 * 4 + r;
                const float g = gamma[ng < NN ? ng : 0];
                const float d2 = fmaxf(-2.f * acc[nr][bc][r], 0.f);
                const float L  = g + be - sqrtf(d2);
                const unsigned bit = 1u << (nr * 8 + bc * 4 + r);
                const float sgn = (evb & bit) ? 1.f : -1.f;
                const float s   = sgn * L;
                const float term = fmaxf(-s, 0.f) + __logf(1.f + __expf(-fabsf(s)));
                accs += (vb & bit) ? term : 0.f;
            }
        }
    }

    // ---- Block reduce + one atomic per block.
#pragma unroll
    for (int o = 32; o > 0; o >>= 1) accs += __shfl_down(accs, o, 64);
    if (lane == 0) s_red[w] = accs;
    __syncthreads();
    if (tid == 0)
        atomicAdd(out, (s_red[0] + s_red[1]) + (s_red[2] + s_red[3]));
}

extern "C" void kernel_launch(void* const* d_in, const int* in_sizes, int n_in,
                              void* d_out, int out_size, void* d_ws, size_t ws_size,
                              hipStream_t stream) {
    const int*   events = (const int*)d_in[0];    // [N,B]
    const float* tarr   = (const float*)d_in[1];  // [B]
    const float* beta   = (const float*)d_in[2];  // [B]
    const float* gamma  = (const float*)d_in[3];  // [N]
    const float* zb     = (const float*)d_in[4];  // [B,D]
    const float* zp     = (const float*)d_in[5];  // [K,N,D]
    float* out = (float*)d_out;

    // Zero the single output word (graph-capture-safe), then one fused kernel.
    hipMemsetAsync(out, 0, (size_t)out_size * sizeof(float), stream);

    dim3 grid(GDIM, GDIM);
    pol2vec_main<<<grid, 256, 0, stream>>>(events, tarr, beta, gamma, zb, zp,
                                           out);
}

// Round 14
// 24.151 us; speedup vs baseline: 1.3008x; 1.3008x over previous
//
#include <hip/hip_runtime.h>
#include <hip/hip_fp16.h>
#include <math.h>

// Problem constants: N=2000 politicians, B=2000 bills, D=32, K(order)=3.
#define NN    2000
#define NB    2000
#define DD    32
#define PAD   2048                 // padded N/B for tiling
#define NOCT  16                   // K=128: octs 0-11 data, 12 poly, 13-15 zero
#define TILE  64                   // block tile: 64 pols x 64 bills
#define GDIM  (PAD / TILE)         // 32
#define NPART (GDIM * GDIM)        // 1024 partials

typedef _Float16 half8   __attribute__((ext_vector_type(8)));
typedef float    float4v __attribute__((ext_vector_type(4)));

// d_ws layout (bytes):
#define ZF_OFF 0                                  // ZfF: [NOCT][PAD][8] f16 = 512KB
#define WF_OFF (NOCT * PAD * 8 * 2)               // WF:  same shape         512KB
#define PT_OFF (2 * (NOCT * PAD * 8 * 2))         // partials: float[NPART]    4KB

// ---- prep (proven r10, absmax 0): fragment-major fp16 operands, K=128 fold.
// k 0..95: [A|B|C] vs [z | t z | (t^2/2) z];  oct 12: [c0..c4,1] vs
// [-1/2, -t/2, -t^2/2, -t^3/2, -t^4/2, -|z|^2/2];  octs 13-15 zero.
// => MFMA gives g = dot - pv/2 - |z|^2/2 = -dist^2/2 directly.
__global__ __launch_bounds__(256) void pol2vec_prep(
    const float* __restrict__ zb, const float* __restrict__ zp,
    const float* __restrict__ tarr,
    _Float16* __restrict__ ZfF, _Float16* __restrict__ WF)
{
    const int u = blockIdx.x * 256 + threadIdx.x;
    const int total = NOCT * PAD;
    float vals[8] = {0.f, 0.f, 0.f, 0.f, 0.f, 0.f, 0.f, 0.f};

    if (u < total) {                              // ----- Zf side
        const int o = u / PAD, b = u - o * PAD;
        if (b < NB) {
            if (o < 12) {
                const float t = tarr[b];
                const float s = (o < 4) ? 1.f : (o < 8) ? t : 0.5f * t * t;
                const float* zrow = zb + (size_t)b * DD + 8 * (o & 3);
#pragma unroll
                for (int i = 0; i < 8; ++i) vals[i] = s * zrow[i];
            } else if (o == 12) {
                const float t = tarr[b];
                const float* zrow = zb + (size_t)b * DD;
                float z2 = 0.f;
#pragma unroll
                for (int d = 0; d < DD; ++d) z2 = fmaf(zrow[d], zrow[d], z2);
                const float t2 = t * t;
                vals[0] = -0.5f;        vals[1] = -0.5f * t;
                vals[2] = -0.5f * t2;   vals[3] = -0.5f * t2 * t;
                vals[4] = -0.5f * t2 * t2;
                vals[5] = -0.5f * z2;
            }
        }
        _Float16* dst = ZfF + (size_t)u * 8;
#pragma unroll
        for (int i = 0; i < 8; ++i) dst[i] = (_Float16)vals[i];
    } else if (u < 2 * total) {                   // ----- W side
        const int u2 = u - total;
        const int o = u2 / PAD, n = u2 - o * PAD;
        if (n < NN) {
            if (o < 12) {
                const int ksel = o >> 2;          // 0:A 1:B 2:C
                const float* src = zp + ((size_t)ksel * NN + n) * DD + 8 * (o & 3);
#pragma unroll
                for (int i = 0; i < 8; ++i) vals[i] = src[i];
            } else if (o == 12) {
                const float* pA = zp + (size_t)n * DD;
                const float* pB = zp + ((size_t)NN + n) * DD;
                const float* pC = zp + ((size_t)2 * NN + n) * DD;
                float aa = 0.f, ab = 0.f, ac = 0.f, bb = 0.f, bc = 0.f, cc = 0.f;
#pragma unroll
                for (int d = 0; d < DD; ++d) {
                    const float a = pA[d], b = pB[d], c = pC[d];
                    aa = fmaf(a, a, aa); ab = fmaf(a, b, ab); ac = fmaf(a, c, ac);
                    bb = fmaf(b, b, bb); bc = fmaf(b, c, bc); cc = fmaf(c, c, cc);
                }
                vals[0] = aa;        vals[1] = 2.f * ab;
                vals[2] = bb + ac;   vals[3] = bc;
                vals[4] = 0.25f * cc;
                vals[5] = 1.f;
            }
        }
        _Float16* dst = WF + (size_t)u2 * 8;
#pragma unroll
        for (int i = 0; i < 8; ++i) dst[i] = (_Float16)vals[i];
    }
}

// ---- main: MFMA K=128 -> -dist^2/2, minimal epilogue (beta/gamma direct),
// block partial to ws. No LDS tables, no atomics, no fences (r9 structure).
__global__ __launch_bounds__(256, 4) void pol2vec_main(
    const int* __restrict__ events,           // [N,B] 0/1
    const _Float16* __restrict__ ZfF, const _Float16* __restrict__ WF,
    const float* __restrict__ gamma, const float* __restrict__ beta,
    float* __restrict__ partials)             // [NPART]
{
    __shared__ float s_red[4];

    const int tid  = threadIdx.x;
    const int lane = tid & 63;
    const int w    = tid >> 6;                // wave 0..3
    const int b0   = blockIdx.x * TILE;       // bill base
    const int n0   = blockIdx.y * TILE;       // politician base
    const int wr   = (w >> 1) * 32;           // wave's pol offset in tile
    const int wc   = (w & 1) * 32;            // wave's bill offset in tile
    const int l15  = lane & 15;
    const int l4   = lane >> 4;

    // Fragment loads: one coalesced 16B/lane load per fragment (4 K-steps).
    half8 af[2][4], bf[2][4];
#pragma unroll
    for (int ks = 0; ks < 4; ++ks) {
        const int oct = 4 * ks + l4;
#pragma unroll
        for (int h = 0; h < 2; ++h) {
            af[h][ks] = *(const half8*)(WF  + ((size_t)oct * PAD + (n0 + wr + 16 * h + l15)) * 8);
            bf[h][ks] = *(const half8*)(ZfF + ((size_t)oct * PAD + (b0 + wc + 16 * h + l15)) * 8);
        }
    }

    // Events gather -> bitmasks (16 independent loads, hidden under MFMA).
    unsigned evb = 0u, vb = 0u;
#pragma unroll
    for (int nr = 0; nr < 2; ++nr)
#pragma unroll
    for (int bc = 0; bc < 2; ++bc)
#pragma unroll
    for (int r = 0; r < 4; ++r) {
        const int ng = n0 + wr + 16 * nr + l4 * 4 + r;
        const int bg = b0 + wc + 16 * bc + l15;
        const bool v = (ng < NN) && (bg < NB);
        const size_t idx = v ? ((size_t)ng * NB + bg) : 0;
        const unsigned bit = 1u << (nr * 8 + bc * 4 + r);
        if (v) vb |= bit;
        if (v && events[idx]) evb |= bit;
    }

    float4v acc[2][2] = {};
#pragma unroll
    for (int nr = 0; nr < 2; ++nr)
#pragma unroll
    for (int bc = 0; bc < 2; ++bc)
#pragma unroll
    for (int ks = 0; ks < 4; ++ks)
        acc[nr][bc] = __builtin_amdgcn_mfma_f32_16x16x32_f16(
            af[nr][ks], bf[bc][ks], acc[nr][bc], 0, 0, 0);

    // Epilogue: acc = -dist^2/2;  L = gamma + beta - dist.
    float accs = 0.f;
#pragma unroll
    for (int bc = 0; bc < 2; ++bc) {
        const int bg = b0 + wc + 16 * bc + l15;
        const float be = beta[bg < NB ? bg : 0];          // coalesced 16-lane
#pragma unroll
        for (int nr = 0; nr < 2; ++nr) {
#pragma unroll
            for (int r = 0; r < 4; ++r) {
                const int ng = n0 + wr + 16 * nr + l4 * 4 + r;
                const float g = gamma[ng < NN ? ng : 0];  // group-broadcast
                const float d2 = fmaxf(-2.f * acc[nr][bc][r], 0.f);
                const float L  = g + be - sqrtf(d2);
                const unsigned bit = 1u << (nr * 8 + bc * 4 + r);
                const float sgn = (evb & bit) ? 1.f : -1.f;
                const float s   = sgn * L;
                const float term = fmaxf(-s, 0.f) + __logf(1.f + __expf(-fabsf(s)));
                accs += (vb & bit) ? term : 0.f;
            }
        }
    }

    // Block partial (no atomics).
#pragma unroll
    for (int o = 32; o > 0; o >>= 1) accs += __shfl_down(accs, o, 64);
    if (lane == 0) s_red[w] = accs;
    __syncthreads();
    if (tid == 0)
        partials[blockIdx.y * GDIM + blockIdx.x] =
            (s_red[0] + s_red[1]) + (s_red[2] + s_red[3]);
}

// ---- reduce: 1024 partials -> d_out[0] (overwrite; poison-proof).
__global__ __launch_bounds__(256) void pol2vec_reduce(
    const float4* __restrict__ p4, float* __restrict__ out)
{
    __shared__ float s_red[4];
    const int tid = threadIdx.x;
    const float4 v = p4[tid];                 // 256 threads x float4 = 1024
    float s = (v.x + v.y) + (v.z + v.w);
#pragma unroll
    for (int o = 32; o > 0; o >>= 1) s += __shfl_down(s, o, 64);
    if ((tid & 63) == 0) s_red[tid >> 6] = s;
    __syncthreads();
    if (tid == 0) out[0] = (s_red[0] + s_red[1]) + (s_red[2] + s_red[3]);
}

extern "C" void kernel_launch(void* const* d_in, const int* in_sizes, int n_in,
                              void* d_out, int out_size, void* d_ws, size_t ws_size,
                              hipStream_t stream) {
    const int*   events = (const int*)d_in[0];    // [N,B]
    const float* tarr   = (const float*)d_in[1];  // [B]
    const float* beta   = (const float*)d_in[2];  // [B]
    const float* gamma  = (const float*)d_in[3];  // [N]
    const float* zb     = (const float*)d_in[4];  // [B,D]
    const float* zp     = (const float*)d_in[5];  // [K,N,D]
    float* out = (float*)d_out;

    _Float16* ZfF   = (_Float16*)((char*)d_ws + ZF_OFF);
    _Float16* WF    = (_Float16*)((char*)d_ws + WF_OFF);
    float*    parts = (float*)((char*)d_ws + PT_OFF);

    const int prep_units = 2 * NOCT * PAD;        // 65536
    pol2vec_prep<<<prep_units / 256, 256, 0, stream>>>(zb, zp, tarr, ZfF, WF);

    dim3 grid(GDIM, GDIM);
    pol2vec_main<<<grid, 256, 0, stream>>>(events, ZfF, WF, gamma, beta, parts);

    pol2vec_reduce<<<1, 256, 0, stream>>>((const float4*)parts, out);
}

// Round 15
// 20.400 us; speedup vs baseline: 1.5400x; 1.1839x over previous
//
#include <hip/hip_runtime.h>
#include <hip/hip_fp16.h>
#include <math.h>

// Problem constants: N=2000 politicians, B=2000 bills, D=32, K(order)=3.
#define NN    2000
#define NB    2000
#define DD    32
#define NOCT  16                   // K=128: octs 0-11 data, 12 poly, 13-15 zero
#define TILE  64                   // block tile: 64 pols x 64 bills
#define GDIM  32                   // 2048/64
#define NPART (GDIM * GDIM)        // 1024 partials

typedef _Float16 half8   __attribute__((ext_vector_type(8)));
typedef _Float16 half4   __attribute__((ext_vector_type(4)));
typedef float    float4v __attribute__((ext_vector_type(4)));

__device__ __forceinline__ float dot4(const float4 a, const float4 b) {
    return fmaf(a.x, b.x, fmaf(a.y, b.y, fmaf(a.z, b.z, a.w * b.w)));
}
__device__ __forceinline__ half4 cvt4(const float x, const float y,
                                      const float z, const float w) {
    half4 h; h[0] = (_Float16)x; h[1] = (_Float16)y;
    h[2] = (_Float16)z; h[3] = (_Float16)w; return h;
}

// Fused main (r13's coalesced build, r12's clean ending): in-block build with
// every global access line-coalesced (8 threads/row), fp16 MFMA K=128 ->
// -dist^2/2, logistic epilogue, block partial to ws. 2 dispatches, no atomics.
__global__ __launch_bounds__(256, 4) void pol2vec_main(
    const int*   __restrict__ events,   // [N,B] 0/1
    const float* __restrict__ tarr,     // [B]
    const float* __restrict__ beta,     // [B]
    const float* __restrict__ gamma,    // [N]
    const float* __restrict__ zb,       // [B,D]
    const float* __restrict__ zp,       // [K,N,D]
    float*       __restrict__ partials) // [NPART]
{
    __shared__ _Float16 sW[NOCT * TILE * 8];   // 16KB
    __shared__ _Float16 sZ[NOCT * TILE * 8];   // 16KB
    __shared__ float    s_red[4];

    const int tid  = threadIdx.x;
    const int lane = tid & 63;
    const int w    = tid >> 6;
    const int b0   = blockIdx.x * TILE;
    const int n0   = blockIdx.y * TILE;
    const int wr   = (w >> 1) * 32;
    const int wc   = (w & 1) * 32;
    const int l15  = lane & 15;
    const int l4   = lane >> 4;

    // ---- Events gather first: 16 independent loads, latency hides under build.
    unsigned evb = 0u, vb = 0u;
#pragma unroll
    for (int nr = 0; nr < 2; ++nr)
#pragma unroll
    for (int bc = 0; bc < 2; ++bc)
#pragma unroll
    for (int r = 0; r < 4; ++r) {
        const int ng = n0 + wr + 16 * nr + l4 * 4 + r;
        const int bg = b0 + wc + 16 * bc + l15;
        const bool v = (ng < NN) && (bg < NB);
        const size_t idx = v ? ((size_t)ng * NB + bg) : 0;
        const unsigned bit = 1u << (nr * 8 + bc * 4 + r);
        if (v) vb |= bit;
        if (v && events[idx]) evb |= bit;
    }

    // ---- Zero octets 13-15 (both operands).
    if (tid < 3 * TILE) {
        const half8 zz = {};
        *(half8*)(sW + ((size_t)(13 * TILE + tid)) * 8) = zz;
        *(half8*)(sZ + ((size_t)(13 * TILE + tid)) * 8) = zz;
    }

    const int row = tid >> 3;          // 0..31 (row within half-tile)
    const int q   = tid & 7;           // float4 index within 32-dim row
    const int hs  = (q & 1) * 4;       // half4 slot within octet row

    // ---- W side: 2 passes x 3 coalesced float4 loads; same registers feed
    // fragment writes AND the 6 coefficient dots (zp read exactly once).
#pragma unroll
    for (int p = 0; p < 2; ++p) {
        const int nl = 32 * p + row;
        const int n  = n0 + nl;
        float4 a4 = {0.f,0.f,0.f,0.f}, b4 = {0.f,0.f,0.f,0.f}, c4 = {0.f,0.f,0.f,0.f};
        if (n < NN) {
            a4 = ((const float4*)(zp + (size_t)n * DD))[q];
            b4 = ((const float4*)(zp + ((size_t)NN + n) * DD))[q];
            c4 = ((const float4*)(zp + ((size_t)2 * NN + n) * DD))[q];
        }
        *(half4*)(sW + ((size_t)((0 + (q >> 1)) * TILE + nl)) * 8 + hs) =
            cvt4(a4.x, a4.y, a4.z, a4.w);
        *(half4*)(sW + ((size_t)((4 + (q >> 1)) * TILE + nl)) * 8 + hs) =
            cvt4(b4.x, b4.y, b4.z, b4.w);
        *(half4*)(sW + ((size_t)((8 + (q >> 1)) * TILE + nl)) * 8 + hs) =
            cvt4(c4.x, c4.y, c4.z, c4.w);

        float paa = dot4(a4, a4), pab = dot4(a4, b4), pac = dot4(a4, c4);
        float pbb = dot4(b4, b4), pbc = dot4(b4, c4), pcc = dot4(c4, c4);
#pragma unroll
        for (int off = 1; off < 8; off <<= 1) {
            paa += __shfl_xor(paa, off); pab += __shfl_xor(pab, off);
            pac += __shfl_xor(pac, off); pbb += __shfl_xor(pbb, off);
            pbc += __shfl_xor(pbc, off); pcc += __shfl_xor(pcc, off);
        }
        if (q == 0) {
            half8 hv = {};
            hv[0] = (_Float16)paa;            // |A|^2
            hv[1] = (_Float16)(2.f * pab);    // 2 A.B
            hv[2] = (_Float16)(pbb + pac);    // |B|^2 + A.C
            hv[3] = (_Float16)pbc;            // B.C
            hv[4] = (_Float16)(0.25f * pcc);  // |C|^2/4
            hv[5] = (_Float16)1.f;
            *(half8*)(sW + ((size_t)(12 * TILE + nl)) * 8) = hv;
        }
    }

    // ---- Zf side: z, t*z, (t^2/2)*z octets + poly row (z2 via shuffles).
#pragma unroll
    for (int p = 0; p < 2; ++p) {
        const int bl = 32 * p + row;
        const int b  = b0 + bl;
        float4 z4 = {0.f,0.f,0.f,0.f};
        float t = 0.f;
        if (b < NB) {
            z4 = ((const float4*)(zb + (size_t)b * DD))[q];
            t  = tarr[b];
        }
        const float th = 0.5f * t * t;
        *(half4*)(sZ + ((size_t)((0 + (q >> 1)) * TILE + bl)) * 8 + hs) =
            cvt4(z4.x, z4.y, z4.z, z4.w);
        *(half4*)(sZ + ((size_t)((4 + (q >> 1)) * TILE + bl)) * 8 + hs) =
            cvt4(t * z4.x, t * z4.y, t * z4.z, t * z4.w);
        *(half4*)(sZ + ((size_t)((8 + (q >> 1)) * TILE + bl)) * 8 + hs) =
            cvt4(th * z4.x, th * z4.y, th * z4.z, th * z4.w);

        float pz2 = dot4(z4, z4);
#pragma unroll
        for (int off = 1; off < 8; off <<= 1) pz2 += __shfl_xor(pz2, off);
        if (q == 0) {
            const float t2 = t * t;
            half8 hv = {};
            hv[0] = (_Float16)(-0.5f);
            hv[1] = (_Float16)(-0.5f * t);
            hv[2] = (_Float16)(-0.5f * t2);
            hv[3] = (_Float16)(-0.5f * t2 * t);
            hv[4] = (_Float16)(-0.5f * t2 * t2);
            hv[5] = (_Float16)(-0.5f * pz2);
            *(half8*)(sZ + ((size_t)(12 * TILE + bl)) * 8) = hv;
        }
    }
    __syncthreads();

    // ---- Fragment loads from LDS (K=128: 4 K-steps). Proven layout.
    half8 af[2][4], bf[2][4];
#pragma unroll
    for (int ks = 0; ks < 4; ++ks) {
        const int oct = 4 * ks + l4;
#pragma unroll
        for (int h = 0; h < 2; ++h) {
            af[h][ks] = *(const half8*)(sW + ((size_t)oct * TILE + wr + 16 * h + l15) * 8);
            bf[h][ks] = *(const half8*)(sZ + ((size_t)oct * TILE + wc + 16 * h + l15) * 8);
        }
    }

    float4v acc[2][2] = {};
#pragma unroll
    for (int nr = 0; nr < 2; ++nr)
#pragma unroll
    for (int bc = 0; bc < 2; ++bc)
#pragma unroll
    for (int ks = 0; ks < 4; ++ks)
        acc[nr][bc] = __builtin_amdgcn_mfma_f32_16x16x32_f16(
            af[nr][ks], bf[bc][ks], acc[nr][bc], 0, 0, 0);

    // ---- Epilogue: acc = -dist^2/2;  L = gamma + beta - dist.
    float accs = 0.f;
#pragma unroll
    for (int bc = 0; bc < 2; ++bc) {
        const int bg = b0 + wc + 16 * bc + l15;
        const float be = beta[bg < NB ? bg : 0];
#pragma unroll
        for (int nr = 0; nr < 2; ++nr) {
#pragma unroll
            for (int r = 0; r < 4; ++r) {
                const int ng = n0 + wr + 16 * nr + l4 * 4 + r;
                const float g = gamma[ng < NN ? ng : 0];
                const float d2 = fmaxf(-2.f * acc[nr][bc][r], 0.f);
                const float L  = g + be - sqrtf(d2);
                const unsigned bit = 1u << (nr * 8 + bc * 4 + r);
                const float sgn = (evb & bit) ? 1.f : -1.f;
                const float s   = sgn * L;
                const float term = fmaxf(-s, 0.f) + __logf(1.f + __expf(-fabsf(s)));
                accs += (vb & bit) ? term : 0.f;
            }
        }
    }

    // ---- Block partial (no atomics, no fences).
#pragma unroll
    for (int o = 32; o > 0; o >>= 1) accs += __shfl_down(accs, o, 64);
    if (lane == 0) s_red[w] = accs;
    __syncthreads();
    if (tid == 0)
        partials[blockIdx.y * GDIM + blockIdx.x] =
            (s_red[0] + s_red[1]) + (s_red[2] + s_red[3]);
}

// Reduce: 1024 partials -> d_out[0] (overwrite; poison-proof).
__global__ __launch_bounds__(256) void pol2vec_reduce(
    const float4* __restrict__ p4, float* __restrict__ out)
{
    __shared__ float s_red[4];
    const int tid = threadIdx.x;
    const float4 v = p4[tid];                 // 256 threads x float4 = 1024
    float s = (v.x + v.y) + (v.z + v.w);
#pragma unroll
    for (int o = 32; o > 0; o >>= 1) s += __shfl_down(s, o, 64);
    if ((tid & 63) == 0) s_red[tid >> 6] = s;
    __syncthreads();
    if (tid == 0) out[0] = (s_red[0] + s_red[1]) + (s_red[2] + s_red[3]);
}

extern "C" void kernel_launch(void* const* d_in, const int* in_sizes, int n_in,
                              void* d_out, int out_size, void* d_ws, size_t ws_size,
                              hipStream_t stream) {
    const int*   events = (const int*)d_in[0];    // [N,B]
    const float* tarr   = (const float*)d_in[1];  // [B]
    const float* beta   = (const float*)d_in[2];  // [B]
    const float* gamma  = (const float*)d_in[3];  // [N]
    const float* zb     = (const float*)d_in[4];  // [B,D]
    const float* zp     = (const float*)d_in[5];  // [K,N,D]
    float* out = (float*)d_out;

    float* parts = (float*)d_ws;                  // [NPART], overwritten

    dim3 grid(GDIM, GDIM);
    pol2vec_main<<<grid, 256, 0, stream>>>(events, tarr, beta, gamma, zb, zp,
                                           parts);
    pol2vec_reduce<<<1, 256, 0, stream>>>((const float4*)parts, out);
}